// Round 1
// baseline (367.779 us; speedup 1.0000x reference)
//
#include <hip/hip_runtime.h>
#include <math.h>

#define INF_F 1.0e12f
#define NB 8
#define HW 512
#define PLANE (HW*HW)          // 262144
#define NPIX (NB*PLANE)        // 2097152

// ---------------- Pass 1: 1D EDT along W, per row, binary input ----------------
// grid (512 rows, 8 batches, 2 masks), block 256. z=0: gt mask, z=1: seg mask.
__global__ __launch_bounds__(256) void edt_pass1(
    const float* __restrict__ outputs, const int* __restrict__ labels,
    float* __restrict__ gt_g, float* __restrict__ seg_g, int* __restrict__ flags)
{
  __shared__ float f[HW];
  __shared__ int sflag;
  const int tid = threadIdx.x;
  const int row = blockIdx.x, b = blockIdx.y, z = blockIdx.z;
  if (tid == 0) sflag = 0;
  __syncthreads();
  const int base1 = (b*2 + 1) * PLANE + row * HW;   // channel-1 plane, this row
  bool any = false;
  for (int e = tid; e < HW; e += 256) {
    const bool m = (z == 0) ? (labels[base1 + e] > 0) : (outputs[base1 + e] > 0.5f);
    f[e] = m ? INF_F : 0.0f;
    any |= m;
  }
  if (any) atomicOr(&sflag, 1);
  __syncthreads();

  // each thread computes outputs i0, i0+1
  const int i0 = tid * 2;
  float acc0 = 3.0e38f, acc1 = 3.0e38f;
  float t0 = (float)i0;               // i0 - j, decremented
  for (int j = 0; j < HW; ++j) {
    const float v = f[j];
    acc0 = fminf(acc0, fmaf(t0, t0, v));
    const float t1 = t0 + 1.0f;
    acc1 = fminf(acc1, fmaf(t1, t1, v));
    t0 -= 1.0f;
  }
  float* __restrict__ gout = (z == 0) ? gt_g : seg_g;
  const int gbase = (b*HW + row) * HW;
  gout[gbase + i0]     = acc0;
  gout[gbase + i0 + 1] = acc1;
  if (tid == 0 && sflag) atomicOr(&flags[z*NB + b], 1);
}

// ------- Pass 2: 1D EDT along H + fused hd-loss partial sum ----------
// grid (32 col-tiles of 16, 8 batches, 2 masks), block 256.
// Each thread: one column c (of 16), 32 consecutive rows, register accumulators.
__global__ __launch_bounds__(256) void edt_pass2_hd(
    const float* __restrict__ gt_g, const float* __restrict__ seg_g,
    const float* __restrict__ outputs, const int* __restrict__ labels,
    const int* __restrict__ flags, double* __restrict__ accum)
{
  __shared__ float tile[16 * 513];   // [c][j], stride 513 -> conflict-free
  __shared__ double wred[4];
  const int tid = threadIdx.x;
  const int ct = blockIdx.x, b = blockIdx.y, z = blockIdx.z;
  const int col0 = ct * 16;
  const float* __restrict__ g = (z == 0) ? gt_g : seg_g;

  for (int idx = tid; idx < HW*16; idx += 256) {
    const int j = idx >> 4, c = idx & 15;
    tile[c*513 + j] = g[(b*HW + j)*HW + col0 + c];
  }
  __syncthreads();

  const int c  = tid & 15;
  const int i0 = (tid >> 4) * 32;
  float acc[32];
#pragma unroll
  for (int k = 0; k < 32; ++k) acc[k] = 3.0e38f;
  const float* __restrict__ tc = &tile[c*513];
  float t = (float)i0;                 // i0 - j
  for (int j = 0; j < HW; ++j) {
    const float v = tc[j];
#pragma unroll
    for (int k = 0; k < 32; ++k) {
      const float u = t + (float)k;    // (i0+k) - j ; exact int in fp32
      acc[k] = fminf(acc[k], fmaf(u, u, v));
    }
    t -= 1.0f;
  }

  const float fs = (flags[z*NB + b] != 0) ? 1.0f : 0.0f;
  const int col = col0 + c;
  double part = 0.0;
#pragma unroll
  for (int k = 0; k < 32; ++k) {
    const int i = i0 + k;
    const float d2 = fminf(acc[k], INF_F) * fs;
    const int off = (b*2 + 1)*PLANE + i*HW + col;
    const float p1   = outputs[off];
    const float labf = (labels[off] > 0) ? 1.0f : 0.0f;
    const float dl = p1 - labf;
    part += (double)(dl * dl * d2);
  }
  for (int off = 32; off > 0; off >>= 1) part += __shfl_down(part, off, 64);
  if ((tid & 63) == 0) wred[tid >> 6] = part;
  __syncthreads();
  if (tid == 0) atomicAdd(&accum[0], wred[0] + wred[1] + wred[2] + wred[3]);
}

// ---------------- Dice + CE reduction ----------------
__global__ __launch_bounds__(256) void reduce_dice_ce(
    const float* __restrict__ outputs, const int* __restrict__ labels,
    double* __restrict__ accum)
{
  __shared__ double wred[4][4];
  const int tid = threadIdx.x;
  const int stride = gridDim.x * 256;
  double dI = 0, dP2 = 0, dL = 0, dCE = 0;
  for (int p = blockIdx.x*256 + tid; p < NPIX; p += stride) {
    const int b = p >> 18, rem = p & (PLANE - 1);
    const float p1 = outputs[(b*2 + 1)*PLANE + rem];
    const float p0 = outputs[(b*2    )*PLANE + rem];
    const int   lab = labels[(b*2 + 1)*PLANE + rem] > 0;
    const float labf = lab ? 1.0f : 0.0f;
    dI  += (double)(p1 * labf);
    dP2 += (double)(p1 * p1);
    dL  += (double)labf;
    const float m   = fmaxf(p0, p1);
    const float lse = m + logf(expf(p0 - m) + expf(p1 - m));
    dCE += (double)((lab ? p1 : p0) - lse);
  }
  for (int off = 32; off > 0; off >>= 1) {
    dI  += __shfl_down(dI,  off, 64);
    dP2 += __shfl_down(dP2, off, 64);
    dL  += __shfl_down(dL,  off, 64);
    dCE += __shfl_down(dCE, off, 64);
  }
  const int w = tid >> 6;
  if ((tid & 63) == 0) { wred[w][0] = dI; wred[w][1] = dP2; wred[w][2] = dL; wred[w][3] = dCE; }
  __syncthreads();
  if (tid < 4) {
    const double s = wred[0][tid] + wred[1][tid] + wred[2][tid] + wred[3][tid];
    atomicAdd(&accum[1 + tid], s);
  }
}

// ---------------- Finalize ----------------
__global__ void finalize(const double* __restrict__ accum, float* __restrict__ out)
{
  const double N = (double)NPIX;
  const double hd   = accum[0] / N;
  const double I    = accum[1], P2 = accum[2], L = accum[3], CE = accum[4];
  const double ce   = -(CE / N);
  const double dice = 1.0 - (2.0*I + 1e-6) / (P2 + L + 1e-6);
  out[0] = (float)(ce + dice + 0.5 * hd);   // LAM=1, 1-ALPHA=0.5
}

extern "C" void kernel_launch(void* const* d_in, const int* in_sizes, int n_in,
                              void* d_out, int out_size, void* d_ws, size_t ws_size,
                              hipStream_t stream)
{
  const float* outputs = (const float*)d_in[0];
  const int*   labels  = (const int*)d_in[1];

  double* accum = (double*)d_ws;                       // accum[0..4]
  int*    flags = (int*)((char*)d_ws + 128);           // flags[16]
  float*  gt_g  = (float*)((char*)d_ws + 256);         // 8*512*512 floats
  float*  seg_g = gt_g + (size_t)NB * PLANE;           // 8*512*512 floats

  hipMemsetAsync(d_ws, 0, 256, stream);
  edt_pass1<<<dim3(HW, NB, 2), 256, 0, stream>>>(outputs, labels, gt_g, seg_g, flags);
  edt_pass2_hd<<<dim3(HW/16, NB, 2), 256, 0, stream>>>(gt_g, seg_g, outputs, labels, flags, accum);
  reduce_dice_ce<<<1024, 256, 0, stream>>>(outputs, labels, accum);
  finalize<<<1, 1, 0, stream>>>(accum, (float*)d_out);
}

// Round 2
// 272.678 us; speedup vs baseline: 1.3488x; 1.3488x over previous
//
#include <hip/hip_runtime.h>
#include <math.h>

#define INF_F 1.0e12f
#define NB 8
#define HW 512
#define PLANE (HW*HW)          // 262144
#define NPIX (NB*PLANE)        // 2097152
#define LOWS  (-(1<<30))
#define HIGHS ( (1<<30))

// ---------------- Pass 1: O(n) 1D EDT along W (binary input), one wave/row ----
// grid (512 rows, 8 batches, 2 masks), block 64. z=0: gt mask, z=1: seg mask.
__global__ __launch_bounds__(64) void edt_pass1(
    const float* __restrict__ outputs, const int* __restrict__ labels,
    float* __restrict__ gt_g, float* __restrict__ seg_g, int* __restrict__ flags)
{
  const int lane = threadIdx.x;
  const int row = blockIdx.x, b = blockIdx.y, z = blockIdx.z;
  const int base1 = (b*2 + 1)*PLANE + row*HW;

  bool bg[8];
  bool fgLocal = false;
  if (z == 0) {
    const int4* p = (const int4*)(labels + base1);
    const int4 a = p[lane*2], c4 = p[lane*2 + 1];
    const int v[8] = {a.x, a.y, a.z, a.w, c4.x, c4.y, c4.z, c4.w};
#pragma unroll
    for (int t = 0; t < 8; ++t) { bg[t] = (v[t] <= 0); fgLocal |= (v[t] > 0); }
  } else {
    const float4* p = (const float4*)(outputs + base1);
    const float4 a = p[lane*2], c4 = p[lane*2 + 1];
    const float v[8] = {a.x, a.y, a.z, a.w, c4.x, c4.y, c4.z, c4.w};
#pragma unroll
    for (int t = 0; t < 8; ++t) { const bool fg = (v[t] > 0.5f); bg[t] = !fg; fgLocal |= fg; }
  }

  const int p0 = lane*8;
  int nl[8], nr[8];
  int carry = LOWS;
#pragma unroll
  for (int t = 0; t < 8; ++t) { if (bg[t]) carry = p0 + t; nl[t] = carry; }
  const int laneLast = carry;
  carry = HIGHS;
#pragma unroll
  for (int t = 7; t >= 0; --t) { if (bg[t]) carry = p0 + t; nr[t] = carry; }
  const int laneFirst = carry;

  // exclusive prefix-max of laneLast over lanes
  int v = laneLast;
#pragma unroll
  for (int off = 1; off < 64; off <<= 1) {
    const int u = __shfl_up(v, off, 64);
    if (lane >= off) v = max(v, u);
  }
  int exclL = __shfl_up(v, 1, 64);
  if (lane == 0) exclL = LOWS;

  // exclusive suffix-min of laneFirst over lanes
  int w = laneFirst;
#pragma unroll
  for (int off = 1; off < 64; off <<= 1) {
    const int u = __shfl_down(w, off, 64);
    if (lane < 64 - off) w = min(w, u);
  }
  int exclR = __shfl_down(w, 1, 64);
  if (lane == 63) exclR = HIGHS;

  const bool rowHasBg = __any(laneLast != LOWS);
  if (lane == 0 && __any(fgLocal)) atomicOr(&flags[z*NB + b], 1);

  float g[8];
#pragma unroll
  for (int t = 0; t < 8; ++t) {
    const int pp = p0 + t;
    const int L = max(nl[t], exclL);
    const int R = min(nr[t], exclR);
    int d = min(pp - L, R - pp);
    d = min(d, 511);                       // safe square
    g[t] = rowHasBg ? (float)(d*d) : INF_F;
  }
  float* __restrict__ gout = (z == 0) ? gt_g : seg_g;
  float4* __restrict__ go4 = (float4*)(gout + (b*HW + row)*HW);
  go4[lane*2]     = make_float4(g[0], g[1], g[2], g[3]);
  go4[lane*2 + 1] = make_float4(g[4], g[5], g[6], g[7]);
}

// ------- Pass 2: 1D EDT along H + fused hd / dice / CE partial sums ----------
// grid (64 col-tiles of 8, 8 batches, 2 masks), block 256.
// acc[k] = min_j (h[j] - 2j*i), h[j] = g[j] + j^2 ; d2 = acc + i^2.
__global__ __launch_bounds__(256) void edt_pass2_hd(
    const float* __restrict__ gt_g, const float* __restrict__ seg_g,
    const float* __restrict__ outputs, const int* __restrict__ labels,
    const int* __restrict__ flags, double* __restrict__ accum)
{
  __shared__ float tile[8 * 514];    // [c][j], stride 514 -> conflict-free b64
  __shared__ double wred[4][5];
  const int tid = threadIdx.x;
  const int ct = blockIdx.x, b = blockIdx.y, z = blockIdx.z;
  const int col0 = ct * 8;
  const float* __restrict__ g = (z == 0) ? gt_g : seg_g;

  for (int idx = tid; idx < 8*HW; idx += 256) {
    const int j = idx >> 3, c = idx & 7;
    tile[c*514 + j] = g[(b*HW + j)*HW + col0 + c] + (float)(j*j);
  }
  __syncthreads();

  const int c  = tid & 7;
  const int i0 = (tid >> 3) * 16;
  float acc[16], ikf[16];
#pragma unroll
  for (int k = 0; k < 16; ++k) { acc[k] = 3.0e38f; ikf[k] = (float)(i0 + k); }
  const float* __restrict__ tc = &tile[c*514];
  float m2j = 0.0f;                     // -2j
  for (int j = 0; j < HW; j += 2) {
    const float2 h2 = *(const float2*)&tc[j];
    const float m2jb = m2j - 2.0f;
#pragma unroll
    for (int k = 0; k < 16; ++k) {
      const float c0 = fmaf(m2j,  ikf[k], h2.x);
      const float c1 = fmaf(m2jb, ikf[k], h2.y);
      acc[k] = fminf(fminf(acc[k], c0), c1);   // -> v_min3_f32
    }
    m2j -= 4.0f;
  }

  const float fs = (flags[z*NB + b] != 0) ? 1.0f : 0.0f;
  const int col = col0 + c;
  const int pb1 = (b*2 + 1)*PLANE;
  double part = 0, dI = 0, dP2 = 0, dL = 0, dCE = 0;
#pragma unroll
  for (int k = 0; k < 16; ++k) {
    const int i = i0 + k;
    const float d2 = fminf(fmaf(ikf[k], ikf[k], acc[k]), INF_F) * fs;
    const int off = pb1 + i*HW + col;
    const float p1 = outputs[off];
    const int   lv = labels[off];
    const float labf = (lv > 0) ? 1.0f : 0.0f;
    const float dl = p1 - labf;
    part += (double)(dl*dl*d2);
    if (z == 1) {
      const float p0v = outputs[off - PLANE];
      dI  += (double)(p1 * labf);
      dP2 += (double)(p1 * p1);
      dL  += (double)labf;
      const float m   = fmaxf(p0v, p1);
      const float lse = m + logf(expf(p0v - m) + expf(p1 - m));
      dCE += (double)(((lv > 0) ? p1 : p0v) - lse);
    }
  }
  for (int off = 32; off > 0; off >>= 1) {
    part += __shfl_down(part, off, 64);
    dI   += __shfl_down(dI,   off, 64);
    dP2  += __shfl_down(dP2,  off, 64);
    dL   += __shfl_down(dL,   off, 64);
    dCE  += __shfl_down(dCE,  off, 64);
  }
  const int w = tid >> 6;
  if ((tid & 63) == 0) {
    wred[w][0] = part; wred[w][1] = dI; wred[w][2] = dP2; wred[w][3] = dL; wred[w][4] = dCE;
  }
  __syncthreads();
  if (tid == 0) {
    atomicAdd(&accum[0], wred[0][0] + wred[1][0] + wred[2][0] + wred[3][0]);
    if (z == 1) {
#pragma unroll
      for (int q = 1; q < 5; ++q)
        atomicAdd(&accum[q], wred[0][q] + wred[1][q] + wred[2][q] + wred[3][q]);
    }
  }
}

// ---------------- Finalize ----------------
__global__ void finalize(const double* __restrict__ accum, float* __restrict__ out)
{
  const double N = (double)NPIX;
  const double hd   = accum[0] / N;
  const double I    = accum[1], P2 = accum[2], L = accum[3], CE = accum[4];
  const double ce   = -(CE / N);
  const double dice = 1.0 - (2.0*I + 1e-6) / (P2 + L + 1e-6);
  out[0] = (float)(ce + dice + 0.5 * hd);   // LAM=1, 1-ALPHA=0.5
}

extern "C" void kernel_launch(void* const* d_in, const int* in_sizes, int n_in,
                              void* d_out, int out_size, void* d_ws, size_t ws_size,
                              hipStream_t stream)
{
  const float* outputs = (const float*)d_in[0];
  const int*   labels  = (const int*)d_in[1];

  double* accum = (double*)d_ws;                       // accum[0..4]
  int*    flags = (int*)((char*)d_ws + 128);           // flags[16]
  float*  gt_g  = (float*)((char*)d_ws + 256);         // 8*512*512 floats
  float*  seg_g = gt_g + (size_t)NB * PLANE;           // 8*512*512 floats

  hipMemsetAsync(d_ws, 0, 256, stream);
  edt_pass1<<<dim3(HW, NB, 2), 64, 0, stream>>>(outputs, labels, gt_g, seg_g, flags);
  edt_pass2_hd<<<dim3(HW/8, NB, 2), 256, 0, stream>>>(gt_g, seg_g, outputs, labels, flags, accum);
  finalize<<<1, 1, 0, stream>>>(accum, (float*)d_out);
}

// Round 3
// 121.507 us; speedup vs baseline: 3.0268x; 2.2441x over previous
//
#include <hip/hip_runtime.h>
#include <math.h>

#define INF_F 1.0e12f
#define NB 8
#define HW 512
#define PLANE (HW*HW)          // 262144
#define NPIX (NB*PLANE)        // 2097152
#define LOWS  (-(1<<30))
#define HIGHS ( (1<<30))
#define TSTR 516               // tile stride: 516 % 32 == 4 -> 2-way (free) on stage

// ---------------- Pass 1: O(n) 1D EDT along W (binary input), one wave/row ----
// grid (128, 8, 2), block 256 = 4 waves = 4 rows. z=0: gt mask, z=1: seg mask.
__global__ __launch_bounds__(256) void edt_pass1(
    const float* __restrict__ outputs, const int* __restrict__ labels,
    float* __restrict__ gt_g, float* __restrict__ seg_g)
{
  const int lane = threadIdx.x & 63;
  const int row  = blockIdx.x*4 + (threadIdx.x >> 6);
  const int b = blockIdx.y, z = blockIdx.z;
  const int base1 = (b*2 + 1)*PLANE + row*HW;

  bool bg[8];
  if (z == 0) {
    const int4* p = (const int4*)(labels + base1);
    const int4 a = p[lane*2], c4 = p[lane*2 + 1];
    const int v[8] = {a.x, a.y, a.z, a.w, c4.x, c4.y, c4.z, c4.w};
#pragma unroll
    for (int t = 0; t < 8; ++t) bg[t] = (v[t] <= 0);
  } else {
    const float4* p = (const float4*)(outputs + base1);
    const float4 a = p[lane*2], c4 = p[lane*2 + 1];
    const float v[8] = {a.x, a.y, a.z, a.w, c4.x, c4.y, c4.z, c4.w};
#pragma unroll
    for (int t = 0; t < 8; ++t) bg[t] = !(v[t] > 0.5f);
  }

  const int p0 = lane*8;
  int nl[8], nr[8];
  int carry = LOWS;
#pragma unroll
  for (int t = 0; t < 8; ++t) { if (bg[t]) carry = p0 + t; nl[t] = carry; }
  const int laneLast = carry;
  carry = HIGHS;
#pragma unroll
  for (int t = 7; t >= 0; --t) { if (bg[t]) carry = p0 + t; nr[t] = carry; }
  const int laneFirst = carry;

  // exclusive prefix-max of laneLast over lanes
  int v = laneLast;
#pragma unroll
  for (int off = 1; off < 64; off <<= 1) {
    const int u = __shfl_up(v, off, 64);
    if (lane >= off) v = max(v, u);
  }
  int exclL = __shfl_up(v, 1, 64);
  if (lane == 0) exclL = LOWS;

  // exclusive suffix-min of laneFirst over lanes
  int w = laneFirst;
#pragma unroll
  for (int off = 1; off < 64; off <<= 1) {
    const int u = __shfl_down(w, off, 64);
    if (lane < 64 - off) w = min(w, u);
  }
  int exclR = __shfl_down(w, 1, 64);
  if (lane == 63) exclR = HIGHS;

  const bool rowHasBg = __any(laneLast != LOWS);

  float g[8];
#pragma unroll
  for (int t = 0; t < 8; ++t) {
    const int pp = p0 + t;
    const int L = max(nl[t], exclL);
    const int R = min(nr[t], exclR);
    int d = min(pp - L, R - pp);
    d = min(d, 511);                       // safe square
    g[t] = rowHasBg ? (float)(d*d) : INF_F;
  }
  float* __restrict__ gout = (z == 0) ? gt_g : seg_g;
  float4* __restrict__ go4 = (float4*)(gout + (b*HW + row)*HW);
  go4[lane*2]     = make_float4(g[0], g[1], g[2], g[3]);
  go4[lane*2 + 1] = make_float4(g[4], g[5], g[6], g[7]);
}

// ------- Pass 2: outward-scan 1D EDT along H + fused hd / dice / CE ----------
// grid (32 col-tiles of 16, 8 batches, 2 masks), block 256.
// d2(i) = min_j g[j]+(i-j)^2 via scan outward from j=i, exit when s^2 >= cur.
// Exact: for s < s*, s^2 < true_min <= m; clamped-border candidates are
// dominated (s > i implies s^2 > i^2, and j=0 is evaluated at s=i).
__global__ __launch_bounds__(256) void edt_pass2_hd(
    const float* __restrict__ gt_g, const float* __restrict__ seg_g,
    const float* __restrict__ outputs, const int* __restrict__ labels,
    double* __restrict__ accum)
{
  __shared__ float tile[16 * TSTR];
  __shared__ double wred[4][5];
  const int tid = threadIdx.x;
  const int ct = blockIdx.x, b = blockIdx.y, z = blockIdx.z;
  const int col0 = ct * 16;
  const float* __restrict__ g = (z == 0) ? gt_g : seg_g;

  // stage 16 cols x 512 rows, 64B-coalesced reads, 2-way-free LDS writes
  for (int idx = tid; idx < HW*4; idx += 256) {
    const int j = idx >> 2, q = idx & 3;
    const float4 v = *((const float4*)(g + (size_t)(b*HW + j)*HW + col0) + q);
    const int cb = q*4;
    tile[(cb+0)*TSTR + j] = v.x;
    tile[(cb+1)*TSTR + j] = v.y;
    tile[(cb+2)*TSTR + j] = v.z;
    tile[(cb+3)*TSTR + j] = v.w;
  }
  __syncthreads();

  const int c     = tid & 15;
  const int ibase = (tid >> 4) * 32;
  const float* __restrict__ tc = &tile[c*TSTR];
  const int col = col0 + c;
  const int pb1 = (b*2 + 1)*PLANE;
  double part = 0, dI = 0, dP2 = 0, dL = 0, dCE = 0;

  for (int k = 0; k < 32; ++k) {
    const int i = ibase + k;
    float m = tc[i];
    float s2 = 1.0f;
    int s = 1;
    while (s2 < m && s < HW) {
      const int jl = (i - s) < 0 ? 0 : (i - s);
      const int jr = (i + s) > (HW-1) ? (HW-1) : (i + s);
      m = fminf(m, fminf(tc[jl] + s2, tc[jr] + s2));
      s2 += (float)(2*s + 1);
      ++s;
    }
    const float d2 = fminf(m, INF_F);
    const int off = pb1 + i*HW + col;
    const float p1 = outputs[off];
    const int   lv = labels[off];
    const float labf = (lv > 0) ? 1.0f : 0.0f;
    const float dl = p1 - labf;
    part += (double)(dl*dl*d2);
    if (z == 1) {
      const float p0v = outputs[off - PLANE];
      dI  += (double)(p1 * labf);
      dP2 += (double)(p1 * p1);
      dL  += (double)labf;
      const float mm  = fmaxf(p0v, p1);
      const float lse = mm + logf(expf(p0v - mm) + expf(p1 - mm));
      dCE += (double)(((lv > 0) ? p1 : p0v) - lse);
    }
  }

  for (int off = 32; off > 0; off >>= 1) {
    part += __shfl_down(part, off, 64);
    dI   += __shfl_down(dI,   off, 64);
    dP2  += __shfl_down(dP2,  off, 64);
    dL   += __shfl_down(dL,   off, 64);
    dCE  += __shfl_down(dCE,  off, 64);
  }
  const int w = tid >> 6;
  if ((tid & 63) == 0) {
    wred[w][0] = part; wred[w][1] = dI; wred[w][2] = dP2; wred[w][3] = dL; wred[w][4] = dCE;
  }
  __syncthreads();
  if (tid == 0) {
    atomicAdd(&accum[0], wred[0][0] + wred[1][0] + wred[2][0] + wred[3][0]);
    if (z == 1) {
#pragma unroll
      for (int q = 1; q < 5; ++q)
        atomicAdd(&accum[q], wred[0][q] + wred[1][q] + wred[2][q] + wred[3][q]);
    }
  }
}

// ---------------- Finalize ----------------
__global__ void finalize(const double* __restrict__ accum, float* __restrict__ out)
{
  const double N = (double)NPIX;
  const double hd   = accum[0] / N;
  const double I    = accum[1], P2 = accum[2], L = accum[3], CE = accum[4];
  const double ce   = -(CE / N);
  const double dice = 1.0 - (2.0*I + 1e-6) / (P2 + L + 1e-6);
  out[0] = (float)(ce + dice + 0.5 * hd);   // LAM=1, 1-ALPHA=0.5
}

extern "C" void kernel_launch(void* const* d_in, const int* in_sizes, int n_in,
                              void* d_out, int out_size, void* d_ws, size_t ws_size,
                              hipStream_t stream)
{
  const float* outputs = (const float*)d_in[0];
  const int*   labels  = (const int*)d_in[1];

  double* accum = (double*)d_ws;                       // accum[0..4]
  float*  gt_g  = (float*)((char*)d_ws + 256);         // 8*512*512 floats
  float*  seg_g = gt_g + (size_t)NB * PLANE;           // 8*512*512 floats

  hipMemsetAsync(d_ws, 0, 64, stream);
  edt_pass1<<<dim3(HW/4, NB, 2), 256, 0, stream>>>(outputs, labels, gt_g, seg_g);
  edt_pass2_hd<<<dim3(HW/16, NB, 2), 256, 0, stream>>>(gt_g, seg_g, outputs, labels, accum);
  finalize<<<1, 1, 0, stream>>>(accum, (float*)d_out);
}

// Round 4
// 104.360 us; speedup vs baseline: 3.5241x; 1.1643x over previous
//
#include <hip/hip_runtime.h>
#include <math.h>
#include <stdint.h>

#define INF_F 1.0e12f
#define NB 8
#define HW 512
#define PLANE (HW*HW)          // 262144
#define NPIX (NB*PLANE)        // 2097152

// Exact-but-slow per-pixel fallback (provably never taken for random masks;
// kept for unconditional exactness). Scans rows outward reading the mask
// straight from global memory.
__device__ __attribute__((noinline)) int exactRecompute(
    const float* __restrict__ outputs, const int* __restrict__ labels,
    int b, int z, int y, int x)
{
  const int base = (b*2 + 1)*PLANE;
  int m = 0x7fffffff;
  for (int ady = 0; ady < HW; ++ady) {
    if (ady*ady >= m) break;
    for (int sgn = 0; sgn < 2; ++sgn) {
      if (sgn && ady == 0) break;
      const int yy = sgn ? (y - ady) : (y + ady);
      if (yy < 0 || yy >= HW) continue;
      const int rb = base + yy*HW;
      const int a2 = ady*ady;
      for (int t = 0; t < HW; ++t) {
        const int c2 = a2 + t*t;
        if (c2 >= m) break;
        bool hit = false;
        const int xl = x - t, xr = x + t;
        if (xl >= 0)
          hit = (z == 0) ? (labels[rb + xl] <= 0) : !(outputs[rb + xl] > 0.5f);
        if (!hit && xr < HW)
          hit = (z == 0) ? (labels[rb + xr] <= 0) : !(outputs[rb + xr] > 0.5f);
        if (hit) { m = c2; break; }
      }
    }
  }
  return m;   // INT_MAX if no background anywhere
}

// nearest set bit left/right of position px in row word w; updates candidate
// min m and unexplored-lower-bound U. Window covers dx in [-px, 47-px].
__device__ __forceinline__ void visitRow(uint64_t w, int px, int a2,
                                         int pL2, int pR2, int& m, int& U)
{
  const uint64_t below = w & (~0ULL >> (63 - px));   // bits 0..px
  const uint64_t above = w >> px;                    // bit0 = px
  if (below) { const int dL = px - (63 - __builtin_clzll(below)); m = min(m, a2 + dL*dL); }
  else        U = min(U, a2 + pL2);
  if (above) { const int dR = __builtin_ctzll(above); m = min(m, a2 + dR*dR); }
  else        U = min(U, a2 + pR2);
}

__device__ __forceinline__ float scanPixel(const uint64_t* __restrict__ W,
    int ry, int px, const float* __restrict__ outputs, const int* __restrict__ labels,
    int b, int z, int y, int x)
{
  const int pL2 = (px + 1)*(px + 1);
  const int pR2 = (48 - px)*(48 - px);
  int m = 0x7fffffff, U = 0x7fffffff;
  visitRow(W[ry], px, 0, pL2, pR2, m, U);
  int ady = 1;
  for (; ady <= 8; ++ady) {
    const int a2 = ady*ady;
    if (a2 >= m) break;                       // unscanned |dy| bound a2 >= m: exact
    visitRow(W[ry - ady], px, a2, pL2, pR2, m, U);
    visitRow(W[ry + ady], px, a2, pL2, pR2, m, U);
  }
  if (ady == 9) U = min(U, 81);               // |dy| >= 9 candidates
  if (m > U) {                                // uncovered candidate could win
    m = exactRecompute(outputs, labels, b, z, y, x);
    if (m == 0x7fffffff) return INF_F;        // all-foreground mask
  }
  return (float)m;                            // exact integer < 2^24
}

// -------- fully fused: bit-mask 2D EDT (both masks) + hd + dice + CE --------
// grid (16,16,8): 32x32 tile per block, 256 threads, 4 px/thread.
__global__ __launch_bounds__(256) void fused_loss(
    const float* __restrict__ outputs, const int* __restrict__ labels,
    double* __restrict__ accum)
{
  __shared__ unsigned short l16[2][48][4];   // 16-col bit chunks
  __shared__ uint64_t W[2][48];              // assembled 48-bit row words
  __shared__ double wred[4][5];
  const int tid = threadIdx.x;
  const int x0 = blockIdx.x * 32, y0 = blockIdx.y * 32, b = blockIdx.z;
  const int base1 = (b*2 + 1)*PLANE;

  // ---- stage: 2 masks x 48 rows x 3 chunks of 16 px -> bit16 each ----
  for (int idx = tid; idx < 288; idx += 256) {
    const int z = idx / 144, rem = idx % 144;
    const int row = rem / 3, ch = rem % 3;
    const int yy = y0 - 8 + row;
    const int xs = x0 - 8 + ch*16;
    uint32_t bits = 0;
    if (yy >= 0 && yy < HW) {
      const int rb = base1 + yy*HW;
      if (xs >= 0 && xs + 16 <= HW) {
        if (z == 0) {
          const int4* p = (const int4*)(labels + rb + xs);
          const int4 a = p[0], c = p[1], d = p[2], e = p[3];
          const int v[16] = {a.x,a.y,a.z,a.w, c.x,c.y,c.z,c.w,
                             d.x,d.y,d.z,d.w, e.x,e.y,e.z,e.w};
#pragma unroll
          for (int t = 0; t < 16; ++t) if (v[t] <= 0) bits |= (1u << t);
        } else {
          const float4* p = (const float4*)(outputs + rb + xs);
          const float4 a = p[0], c = p[1], d = p[2], e = p[3];
          const float v[16] = {a.x,a.y,a.z,a.w, c.x,c.y,c.z,c.w,
                               d.x,d.y,d.z,d.w, e.x,e.y,e.z,e.w};
#pragma unroll
          for (int t = 0; t < 16; ++t) if (!(v[t] > 0.5f)) bits |= (1u << t);
        }
      } else {
        for (int t = 0; t < 16; ++t) {
          const int xx = xs + t;
          if (xx < 0 || xx >= HW) continue;
          const bool bg = (z == 0) ? (labels[rb + xx] <= 0)
                                   : !(outputs[rb + xx] > 0.5f);
          if (bg) bits |= (1u << t);
        }
      }
    }
    l16[z][row][ch] = (unsigned short)bits;
  }
  __syncthreads();
  if (tid < 96) {
    const int z = tid / 48, row = tid % 48;
    W[z][row] = (uint64_t)l16[z][row][0]
              | ((uint64_t)l16[z][row][1] << 16)
              | ((uint64_t)l16[z][row][2] << 32);
  }
  __syncthreads();

  // ---- per-pixel EDT scan + fused reductions ----
  const int lx = tid & 31, lyb = tid >> 5;
  const int px = 8 + lx;
  const int x = x0 + lx;
  double part = 0, dI = 0, dP2 = 0, dLs = 0, dCE = 0;
#pragma unroll
  for (int k = 0; k < 4; ++k) {
    const int ly = lyb + 8*k;
    const int y = y0 + ly;
    const int ry = 8 + ly;
    const float d2g = scanPixel(W[0], ry, px, outputs, labels, b, 0, y, x);
    const float d2s = scanPixel(W[1], ry, px, outputs, labels, b, 1, y, x);
    const int off = base1 + y*HW + x;
    const float p1  = outputs[off];
    const float p0v = outputs[off - PLANE];
    const int   lv  = labels[off];
    const float labf = (lv > 0) ? 1.0f : 0.0f;
    const float dl = p1 - labf;
    part += (double)(dl*dl*d2g) + (double)(dl*dl*d2s);
    dI  += (double)(p1 * labf);
    dP2 += (double)(p1 * p1);
    dLs += (double)labf;
    const float mm  = fmaxf(p0v, p1);
    const float lse = mm + logf(expf(p0v - mm) + expf(p1 - mm));
    dCE += (double)(((lv > 0) ? p1 : p0v) - lse);
  }

  for (int off = 32; off > 0; off >>= 1) {
    part += __shfl_down(part, off, 64);
    dI   += __shfl_down(dI,   off, 64);
    dP2  += __shfl_down(dP2,  off, 64);
    dLs  += __shfl_down(dLs,  off, 64);
    dCE  += __shfl_down(dCE,  off, 64);
  }
  const int w = tid >> 6;
  if ((tid & 63) == 0) {
    wred[w][0] = part; wred[w][1] = dI; wred[w][2] = dP2; wred[w][3] = dLs; wred[w][4] = dCE;
  }
  __syncthreads();
  if (tid < 5) {
    atomicAdd(&accum[tid], wred[0][tid] + wred[1][tid] + wred[2][tid] + wred[3][tid]);
  }
}

// ---------------- Finalize ----------------
__global__ void finalize(const double* __restrict__ accum, float* __restrict__ out)
{
  const double N = (double)NPIX;
  const double hd   = accum[0] / N;
  const double I    = accum[1], P2 = accum[2], L = accum[3], CE = accum[4];
  const double ce   = -(CE / N);
  const double dice = 1.0 - (2.0*I + 1e-6) / (P2 + L + 1e-6);
  out[0] = (float)(ce + dice + 0.5 * hd);   // LAM=1, 1-ALPHA=0.5
}

extern "C" void kernel_launch(void* const* d_in, const int* in_sizes, int n_in,
                              void* d_out, int out_size, void* d_ws, size_t ws_size,
                              hipStream_t stream)
{
  const float* outputs = (const float*)d_in[0];
  const int*   labels  = (const int*)d_in[1];
  double* accum = (double*)d_ws;   // accum[0..4]

  hipMemsetAsync(d_ws, 0, 64, stream);
  fused_loss<<<dim3(16, 16, NB), 256, 0, stream>>>(outputs, labels, accum);
  finalize<<<1, 1, 0, stream>>>(accum, (float*)d_out);
}

// Round 5
// 92.793 us; speedup vs baseline: 3.9634x; 1.1246x over previous
//
#include <hip/hip_runtime.h>
#include <math.h>
#include <stdint.h>

#define INF_F 1.0e12f
#define NB 8
#define HW 512
#define PLANE (HW*HW)          // 262144
#define NPIX (NB*PLANE)        // 2097152
#define NBLK (16*16*NB)        // 2048 blocks

// Exact-but-slow per-pixel fallback (certificate m<=16 fails ~never for random
// masks; kept for unconditional exactness). Reads the mask from global memory.
__device__ __attribute__((noinline)) int exactRecompute(
    const float* __restrict__ outputs, const int* __restrict__ labels,
    int b, int z, int y, int x)
{
  const int base = (b*2 + 1)*PLANE;
  int m = 0x7fffffff;
  for (int ady = 0; ady < HW; ++ady) {
    if (ady*ady >= m) break;
    for (int sgn = 0; sgn < 2; ++sgn) {
      if (sgn && ady == 0) break;
      const int yy = sgn ? (y - ady) : (y + ady);
      if (yy < 0 || yy >= HW) continue;
      const int rb = base + yy*HW;
      const int a2 = ady*ady;
      for (int t = 0; t < HW; ++t) {
        const int c2 = a2 + t*t;
        if (c2 >= m) break;
        bool hit = false;
        const int xl = x - t, xr = x + t;
        if (xl >= 0)
          hit = (z == 0) ? (labels[rb + xl] <= 0) : !(outputs[rb + xl] > 0.5f);
        if (!hit && xr < HW)
          hit = (z == 0) ? (labels[rb + xr] <= 0) : !(outputs[rb + xr] > 0.5f);
        if (hit) { m = c2; break; }
      }
    }
  }
  return m;   // INT_MAX if no background anywhere
}

// -------- fully fused: bit-mask 2D EDT (both masks) + hd + dice + CE --------
// grid (16,16,8): 32x32 tile per block, 256 threads, 4 consecutive rows/thread.
// Branch-free bounded scan |dy|<=3; exact when m<=16 (halo=8 => side exits
// >= 81, unscanned rows >= 16); else rare exact fallback.
__global__ __launch_bounds__(256) void fused_loss(
    const float* __restrict__ outputs, const int* __restrict__ labels,
    double* __restrict__ partials)
{
  __shared__ unsigned short l16[2][48][4];   // 16-col bit chunks
  __shared__ uint64_t W[2][48];              // assembled 48-bit row words
  __shared__ double wred[4][5];
  const int tid = threadIdx.x;
  const int x0 = blockIdx.x * 32, y0 = blockIdx.y * 32, b = blockIdx.z;
  const int base1 = (b*2 + 1)*PLANE;

  // ---- stage: 2 masks x 48 rows x 3 chunks of 16 px -> bit16 each ----
  for (int idx = tid; idx < 288; idx += 256) {
    const int z = idx / 144, rem = idx % 144;
    const int row = rem / 3, ch = rem % 3;
    const int yy = y0 - 8 + row;
    const int xs = x0 - 8 + ch*16;
    uint32_t bits = 0;
    if (yy >= 0 && yy < HW) {
      const int rb = base1 + yy*HW;
      if (xs >= 0 && xs + 16 <= HW) {
        if (z == 0) {
          const int4* p = (const int4*)(labels + rb + xs);
          const int4 a = p[0], c = p[1], d = p[2], e = p[3];
          const int v[16] = {a.x,a.y,a.z,a.w, c.x,c.y,c.z,c.w,
                             d.x,d.y,d.z,d.w, e.x,e.y,e.z,e.w};
#pragma unroll
          for (int t = 0; t < 16; ++t) if (v[t] <= 0) bits |= (1u << t);
        } else {
          const float4* p = (const float4*)(outputs + rb + xs);
          const float4 a = p[0], c = p[1], d = p[2], e = p[3];
          const float v[16] = {a.x,a.y,a.z,a.w, c.x,c.y,c.z,c.w,
                               d.x,d.y,d.z,d.w, e.x,e.y,e.z,e.w};
#pragma unroll
          for (int t = 0; t < 16; ++t) if (!(v[t] > 0.5f)) bits |= (1u << t);
        }
      } else {
        for (int t = 0; t < 16; ++t) {
          const int xx = xs + t;
          if (xx < 0 || xx >= HW) continue;
          const bool bg = (z == 0) ? (labels[rb + xx] <= 0)
                                   : !(outputs[rb + xx] > 0.5f);
          if (bg) bits |= (1u << t);
        }
      }
    }
    l16[z][row][ch] = (unsigned short)bits;
  }
  __syncthreads();
  if (tid < 96) {
    const int z = tid / 48, row = tid % 48;
    W[z][row] = (uint64_t)l16[z][row][0]
              | ((uint64_t)l16[z][row][1] << 16)
              | ((uint64_t)l16[z][row][2] << 32);
  }
  __syncthreads();

  // ---- branch-free per-pixel EDT: 4 consecutive rows per thread ----
  const int lx = tid & 31, lyb = tid >> 5;
  const int px = 8 + lx, sh = 63 - px;
  const int x = x0 + lx;
  const int ry0 = 8 + lyb*4;                 // window row of first pixel

  float d2m[2][4];
#pragma unroll
  for (int z = 0; z < 2; ++z) {
    const uint64_t* __restrict__ Wz = W[z];
    int rd2[10];                             // per-row nearest-dist^2 (63 cap)
#pragma unroll
    for (int j = 0; j < 10; ++j) {
      const uint64_t w = Wz[ry0 - 3 + j];
      const int dL = __builtin_clzll((w << sh) | 1ull);          // empty -> 63
      const int dR = __builtin_ctzll((w >> px) | (1ull << 63));  // empty -> 63
      const int d = min(dL, dR);
      rd2[j] = d*d;
    }
#pragma unroll
    for (int k = 0; k < 4; ++k) {
      int m = rd2[k+3];
      m = min(m, 1 + min(rd2[k+2], rd2[k+4]));
      m = min(m, 4 + min(rd2[k+1], rd2[k+5]));
      m = min(m, 9 + min(rd2[k+0], rd2[k+6]));
      float d2;
      if (__builtin_expect(m > 16, 0)) {     // certificate failed: exact fallback
        const int mr = exactRecompute(outputs, labels, b, z, y0 + lyb*4 + k, x);
        d2 = (mr == 0x7fffffff) ? INF_F : (float)mr;
      } else {
        d2 = (float)m;
      }
      d2m[z][k] = d2;
    }
  }

  // ---- fused hd / dice / CE (fp32 partials over 4 px, widen to f64) ----
  float part = 0, fI = 0, fP2 = 0, fL = 0, fCE = 0;
#pragma unroll
  for (int k = 0; k < 4; ++k) {
    const int y = y0 + lyb*4 + k;
    const int off = base1 + y*HW + x;
    const float p1  = outputs[off];
    const float p0v = outputs[off - PLANE];
    const int   lv  = labels[off];
    const float labf = (lv > 0) ? 1.0f : 0.0f;
    const float dl = p1 - labf;
    part = fmaf(dl*dl, d2m[0][k] + d2m[1][k], part);
    fI   = fmaf(p1, labf, fI);
    fP2  = fmaf(p1, p1, fP2);
    fL  += labf;
    const float mm  = fmaxf(p0v, p1);
    const float lse = mm + __logf(1.0f + __expf(fminf(p0v, p1) - mm));
    fCE += ((lv > 0) ? p1 : p0v) - lse;
  }

  double s0 = part, s1 = fI, s2 = fP2, s3 = fL, s4 = fCE;
  for (int off = 32; off > 0; off >>= 1) {
    s0 += __shfl_down(s0, off, 64);
    s1 += __shfl_down(s1, off, 64);
    s2 += __shfl_down(s2, off, 64);
    s3 += __shfl_down(s3, off, 64);
    s4 += __shfl_down(s4, off, 64);
  }
  const int w = tid >> 6;
  if ((tid & 63) == 0) {
    wred[w][0] = s0; wred[w][1] = s1; wred[w][2] = s2; wred[w][3] = s3; wred[w][4] = s4;
  }
  __syncthreads();
  if (tid < 5) {
    const int bid = (blockIdx.z*16 + blockIdx.y)*16 + blockIdx.x;
    partials[tid*NBLK + bid] =
        wred[0][tid] + wred[1][tid] + wred[2][tid] + wred[3][tid];
  }
}

// ---------------- Finalize: reduce 2048 block-partials, compute loss --------
__global__ __launch_bounds__(256) void finalize(
    const double* __restrict__ partials, float* __restrict__ out)
{
  __shared__ double wred[4][5];
  const int tid = threadIdx.x;
  double s[5] = {0, 0, 0, 0, 0};
  for (int i = tid; i < NBLK; i += 256) {
#pragma unroll
    for (int q = 0; q < 5; ++q) s[q] += partials[q*NBLK + i];
  }
  for (int off = 32; off > 0; off >>= 1) {
#pragma unroll
    for (int q = 0; q < 5; ++q) s[q] += __shfl_down(s[q], off, 64);
  }
  const int w = tid >> 6;
  if ((tid & 63) == 0) {
#pragma unroll
    for (int q = 0; q < 5; ++q) wred[w][q] = s[q];
  }
  __syncthreads();
  if (tid == 0) {
#pragma unroll
    for (int q = 0; q < 5; ++q) s[q] = wred[0][q] + wred[1][q] + wred[2][q] + wred[3][q];
    const double N = (double)NPIX;
    const double hd   = s[0] / N;
    const double ce   = -(s[4] / N);
    const double dice = 1.0 - (2.0*s[1] + 1e-6) / (s[2] + s[3] + 1e-6);
    out[0] = (float)(ce + dice + 0.5 * hd);   // LAM=1, 1-ALPHA=0.5
  }
}

extern "C" void kernel_launch(void* const* d_in, const int* in_sizes, int n_in,
                              void* d_out, int out_size, void* d_ws, size_t ws_size,
                              hipStream_t stream)
{
  const float* outputs = (const float*)d_in[0];
  const int*   labels  = (const int*)d_in[1];
  double* partials = (double*)d_ws;   // [5][NBLK] doubles = 80 KB

  fused_loss<<<dim3(16, 16, NB), 256, 0, stream>>>(outputs, labels, partials);
  finalize<<<1, 256, 0, stream>>>(partials, (float*)d_out);
}